// Round 4
// baseline (1961.463 us; speedup 1.0000x reference)
//
#include <hip/hip_runtime.h>

#define HID 128
#define SCAN_T 1024

// NOTE (harness contract): integer inputs arrive as int32 regardless of the
// reference's int64 — edge_index and batch MUST be read as const int*.
// Reading them as long long was the round-3 core dump (garbage indices ->
// scattered atomics -> memory fault).

// ---------------- CSR build ----------------
__global__ void k_hist(const int* __restrict__ dst, int* __restrict__ deg, int e) {
    int i = blockIdx.x * blockDim.x + threadIdx.x;
    if (i < e) atomicAdd(&deg[dst[i]], 1);
}

__global__ void k_scan(const int* __restrict__ deg, int* __restrict__ rs,
                       int* __restrict__ cur, int n) {
    __shared__ int part[SCAN_T];
    int t = threadIdx.x;
    int chunk = (n + SCAN_T - 1) / SCAN_T;
    int b = t * chunk;
    int e = min(b + chunk, n);
    int s = 0;
    for (int i = b; i < e; ++i) s += deg[i];
    part[t] = s;
    __syncthreads();
    for (int off = 1; off < SCAN_T; off <<= 1) {
        int v = part[t];
        int add = (t >= off) ? part[t - off] : 0;
        __syncthreads();
        part[t] = v + add;
        __syncthreads();
    }
    int base = part[t] - s;   // exclusive prefix of this thread's chunk
    int run = base;
    for (int i = b; i < e; ++i) {
        rs[i] = run;
        cur[i] = run;
        run += deg[i];
    }
    if (t == SCAN_T - 1) rs[n] = run;  // == E
}

__global__ void k_scatter(const int* __restrict__ src, const int* __restrict__ dst,
                          int* __restrict__ cur, int* __restrict__ csr, int e) {
    int i = blockIdx.x * blockDim.x + threadIdx.x;
    if (i < e) {
        int d = dst[i];
        int pos = atomicAdd(&cur[d], 1);
        csr[pos] = src[i];
    }
}

// ---------------- gather-aggregate: agg[i] = x[i] + sum_{j in CSR[i]} x[j] ----------------
__global__ __launch_bounds__(256)
void k_gather(const float* __restrict__ x, const int* __restrict__ rs,
              const int* __restrict__ csr, float* __restrict__ agg, int n) {
    int wave = (blockIdx.x * blockDim.x + threadIdx.x) >> 6;
    int lane = threadIdx.x & 63;
    if (wave >= n) return;
    int beg = rs[wave], end = rs[wave + 1];
    const float2* xp = reinterpret_cast<const float2*>(x);
    float2 acc = xp[(size_t)wave * 64 + lane];
    int j = beg;
    for (; j + 4 <= end; j += 4) {
        int s0 = csr[j], s1 = csr[j + 1], s2 = csr[j + 2], s3 = csr[j + 3];
        float2 v0 = xp[(size_t)s0 * 64 + lane];
        float2 v1 = xp[(size_t)s1 * 64 + lane];
        float2 v2 = xp[(size_t)s2 * 64 + lane];
        float2 v3 = xp[(size_t)s3 * 64 + lane];
        acc.x += (v0.x + v1.x) + (v2.x + v3.x);
        acc.y += (v0.y + v1.y) + (v2.y + v3.y);
    }
    for (; j < end; ++j) {
        int s = csr[j];
        float2 v = xp[(size_t)s * 64 + lane];
        acc.x += v.x;
        acc.y += v.y;
    }
    reinterpret_cast<float2*>(agg)[(size_t)wave * 64 + lane] = acc;
}

// ---------------- row-streamed fp32 GEMM: out[r][c] = A[r][:] . W[:][c] + bias[c] ----------------
// One column per lane; W column held in 128 VGPRs per wave; A row read wave-uniform.
// 4 accumulators break the FMA dependency chain. 512 blocks * 4 waves = 2048 waves
// = exactly resident at 2 waves/SIMD (tail-free).
// BN_STATS: per-channel sum/sumsq in double (atomic f64).  FUSE_OUT: out = relu(acc+b)+xres.
// Aliasing notes: out==A is safe only if A fully consumed first (we never do that);
// out==xres is safe (same thread reads then writes the same element);
// out==agg-of-this-layer is safe (agg consumed by the earlier GEMM1 dispatch).
template <bool BN_STATS, bool FUSE_OUT>
__global__ __launch_bounds__(256, 2)
void k_gemm(const float* __restrict__ A, const float* __restrict__ W,
            const float* __restrict__ bias, float* __restrict__ out,
            const float* __restrict__ xres, double* __restrict__ bn_sum,
            double* __restrict__ bn_sq, int nrows) {
    int wave = (blockIdx.x * blockDim.x + threadIdx.x) >> 6;
    int lane = threadIdx.x & 63;
    int half = wave & 1;          // which 64-column half
    int row0 = wave >> 1;         // row stream id
    int nstreams = (gridDim.x * blockDim.x) >> 7;
    int col = half * 64 + lane;

    float w[HID];
#pragma unroll
    for (int k = 0; k < HID; ++k) w[k] = W[k * HID + col];  // coalesced 256B per instr
    float b = bias[col];

    double s0 = 0.0, s1 = 0.0;

    for (int row = row0; row < nrows; row += nstreams) {
        int r = __builtin_amdgcn_readfirstlane(row);
        const float4* a4 = reinterpret_cast<const float4*>(A + (size_t)r * HID);
        float acc0 = 0.f, acc1 = 0.f, acc2 = 0.f, acc3 = 0.f;
#pragma unroll
        for (int kk = 0; kk < HID / 4; ++kk) {
            float4 av = a4[kk];
            acc0 = fmaf(av.x, w[4 * kk + 0], acc0);
            acc1 = fmaf(av.y, w[4 * kk + 1], acc1);
            acc2 = fmaf(av.z, w[4 * kk + 2], acc2);
            acc3 = fmaf(av.w, w[4 * kk + 3], acc3);
        }
        float v = ((acc0 + acc1) + (acc2 + acc3)) + b;
        if (FUSE_OUT) v = fmaxf(v, 0.f) + xres[(size_t)r * HID + col];
        out[(size_t)r * HID + col] = v;
        if (BN_STATS) {
            double vd = (double)v;
            s0 += vd;
            s1 = fma(vd, vd, s1);
        }
    }
    if (BN_STATS) {
        atomicAdd(&bn_sum[col], s0);
        atomicAdd(&bn_sq[col], s1);
    }
}

// ---------------- BN finalize: scale/shift per channel; self-zero stats for next layer ----
__global__ void k_bnfinal(double* __restrict__ sum, double* __restrict__ sq,
                          const float* __restrict__ gamma, const float* __restrict__ beta,
                          float* __restrict__ scale, float* __restrict__ shift, double inv_n) {
    int c = threadIdx.x;
    double m = sum[c] * inv_n;
    double var = sq[c] * inv_n - m * m;
    float sc = gamma[c] * rsqrtf((float)var + 1e-5f);
    scale[c] = sc;
    shift[c] = beta[c] - (float)m * sc;
    sum[c] = 0.0;   // ready for next layer's GEMM1 atomics
    sq[c] = 0.0;
}

// ---------------- BN apply + ReLU, in place ----------------
__global__ void k_bnapply(float* __restrict__ h, const float* __restrict__ scale,
                          const float* __restrict__ shift, int n4) {
    const float4* sc4 = reinterpret_cast<const float4*>(scale);
    const float4* sh4 = reinterpret_cast<const float4*>(shift);
    float4* h4 = reinterpret_cast<float4*>(h);
    int stride = gridDim.x * blockDim.x;
    for (int i = blockIdx.x * blockDim.x + threadIdx.x; i < n4; i += stride) {
        float4 v = h4[i];
        int c = i & 31;  // 32 float4 per 128-wide row
        float4 a = sc4[c], bb = sh4[c];
        v.x = fmaxf(fmaf(v.x, a.x, bb.x), 0.f);
        v.y = fmaxf(fmaf(v.y, a.y, bb.y), 0.f);
        v.z = fmaxf(fmaf(v.z, a.z, bb.z), 0.f);
        v.w = fmaxf(fmaf(v.w, a.w, bb.w), 0.f);
        h4[i] = v;
    }
}

// ---------------- global_add_pool over sorted batch (int32) ----------------
__global__ void k_pool(const float* __restrict__ xf, const int* __restrict__ batch,
                       float* __restrict__ pooled, int n) {
    int g = blockIdx.x;
    int lo = 0, hi = n;
    while (lo < hi) { int mid = (lo + hi) >> 1; if (batch[mid] < g) lo = mid + 1; else hi = mid; }
    int beg = lo;
    lo = 0; hi = n;
    int g1 = g + 1;
    while (lo < hi) { int mid = (lo + hi) >> 1; if (batch[mid] < g1) lo = mid + 1; else hi = mid; }
    int end = lo;
    int t = threadIdx.x;
    float a0 = 0.f, a1 = 0.f, a2 = 0.f, a3 = 0.f;
    int r = beg;
    for (; r + 4 <= end; r += 4) {
        a0 += xf[(size_t)(r + 0) * HID + t];
        a1 += xf[(size_t)(r + 1) * HID + t];
        a2 += xf[(size_t)(r + 2) * HID + t];
        a3 += xf[(size_t)(r + 3) * HID + t];
    }
    for (; r < end; ++r) a0 += xf[(size_t)r * HID + t];
    pooled[(size_t)blockIdx.x * HID + t] = (a0 + a1) + (a2 + a3);
}

extern "C" void kernel_launch(void* const* d_in, const int* in_sizes, int n_in,
                              void* d_out, int out_size, void* d_ws, size_t ws_size,
                              hipStream_t stream) {
    const float* x      = (const float*)d_in[0];
    const int* ei       = (const int*)d_in[1];   // int32 per harness contract!
    const int* batch    = (const int*)d_in[2];   // int32
    const float* W1     = (const float*)d_in[3];
    const float* b1     = (const float*)d_in[4];
    const float* gamma  = (const float*)d_in[5];
    const float* beta   = (const float*)d_in[6];
    const float* W2     = (const float*)d_in[7];
    const float* b2     = (const float*)d_in[8];

    const int N = in_sizes[0] / HID;
    const int E = in_sizes[1] / 2;
    const int L = in_sizes[3] / (HID * HID);
    const int G = (out_size - N * HID) / HID;

    const int* esrc = ei;
    const int* edst = ei + E;

    char* ws = (char*)d_ws;
    size_t off = 0;
    auto alloc = [&](size_t bytes) {
        void* p = ws + off;
        off += (bytes + 255) & ~(size_t)255;
        return p;
    };
    // ~110MB of workspace. The d_out node-feature region doubles as the second
    // ping-pong buffer (dead until the final GEMM2 fully overwrites it).
    float* bufA = (float*)alloc((size_t)N * HID * 4);
    float* bufh = (float*)alloc((size_t)N * HID * 4);
    int* deg = (int*)alloc((size_t)N * 4);
    int* rs  = (int*)alloc(((size_t)N + 1) * 4);
    int* cur = (int*)alloc((size_t)N * 4);
    int* csr = (int*)alloc((size_t)E * 4);
    double* bn_sum  = (double*)alloc(HID * 8);
    double* bn_sq   = (double*)alloc(HID * 8);
    float* bn_scale = (float*)alloc(HID * 4);
    float* bn_shift = (float*)alloc(HID * 4);
    (void)ws_size;

    float* xout   = (float*)d_out;                    // final node features
    float* pooled = (float*)d_out + (size_t)N * HID;  // graph pooled features
    float* bufB   = xout;                             // scratch role during layers

    // CSR by destination (rebuilt every call; identical work each call)
    hipMemsetAsync(deg, 0, (size_t)N * 4, stream);
    hipMemsetAsync(bn_sum, 0, HID * 8, stream);
    hipMemsetAsync(bn_sq, 0, HID * 8, stream);
    k_hist<<<(E + 255) / 256, 256, 0, stream>>>(edst, deg, E);
    k_scan<<<1, SCAN_T, 0, stream>>>(deg, rs, cur, N);
    k_scatter<<<(E + 255) / 256, 256, 0, stream>>>(esrc, edst, cur, csr, E);

    // Buffer schedule (L=4): agg alternates A, B(=d_out), A, B; out = agg region,
    // except the last layer writes xout (same region as its agg — agg already consumed).
    //  l0: gather x->A,  G1 A->H, G2 H+x  -> A
    //  l1: gather A->B,  G1 B->H, G2 H+A  -> B
    //  l2: gather B->A,  G1 A->H, G2 H+B  -> A
    //  l3: gather A->B,  G1 B->H, G2 H+A  -> xout(==B region)
    const float* xl = x;
    for (int l = 0; l < L; ++l) {
        float* agg  = (l & 1) ? bufB : bufA;
        float* outb = (l == L - 1) ? xout : agg;

        k_gather<<<(N * 64 + 255) / 256, 256, 0, stream>>>(xl, rs, csr, agg, N);

        k_gemm<true, false><<<512, 256, 0, stream>>>(
            agg, W1 + (size_t)l * HID * HID, b1 + (size_t)l * HID, bufh,
            nullptr, bn_sum, bn_sq, N);
        k_bnfinal<<<1, HID, 0, stream>>>(bn_sum, bn_sq, gamma + (size_t)l * HID,
                                         beta + (size_t)l * HID, bn_scale, bn_shift,
                                         1.0 / (double)N);
        k_bnapply<<<2048, 256, 0, stream>>>(bufh, bn_scale, bn_shift, N * (HID / 4));
        k_gemm<false, true><<<512, 256, 0, stream>>>(
            bufh, W2 + (size_t)l * HID * HID, b2 + (size_t)l * HID, outb,
            xl, nullptr, nullptr, N);
        xl = outb;
    }

    k_pool<<<G, HID, 0, stream>>>(xout, batch, pooled, N);
}

// Round 5
// 1738.954 us; speedup vs baseline: 1.1280x; 1.1280x over previous
//
#include <hip/hip_runtime.h>

#define HID 128
#define SB 1024

// NOTE (harness contract): integer inputs arrive as int32 — edge_index and
// batch MUST be read as const int* (int64 cast was the round-3 core dump).

// ---------------- CSR build ----------------
__global__ void k_hist(const int* __restrict__ dst, int* __restrict__ deg, int e) {
    int i = blockIdx.x * blockDim.x + threadIdx.x;
    if (i < e) atomicAdd(&deg[dst[i]], 1);
}

// phase 1: block-local scan; rs[i] = exclusive prefix within block; partials[b] = block sum
__global__ __launch_bounds__(SB)
void k_scan1(const int* __restrict__ deg, int* __restrict__ rs,
             int* __restrict__ partials, int n) {
    __shared__ int sh[SB];
    int t = threadIdx.x;
    int i = blockIdx.x * SB + t;
    int v = (i < n) ? deg[i] : 0;
    sh[t] = v;
    __syncthreads();
    for (int off = 1; off < SB; off <<= 1) {
        int add = (t >= off) ? sh[t - off] : 0;
        __syncthreads();
        sh[t] += add;
        __syncthreads();
    }
    if (i < n) rs[i] = sh[t] - v;
    if (t == SB - 1) partials[blockIdx.x] = sh[t];
}

// phase 2: single-block exclusive scan of <=256 partials; also writes rs[n] = total (=E)
__global__ __launch_bounds__(256)
void k_scan2(int* __restrict__ partials, int* __restrict__ rs, int nb, int n) {
    __shared__ int sh[256];
    int t = threadIdx.x;
    int v = (t < nb) ? partials[t] : 0;
    sh[t] = v;
    __syncthreads();
    for (int off = 1; off < 256; off <<= 1) {
        int add = (t >= off) ? sh[t - off] : 0;
        __syncthreads();
        sh[t] += add;
        __syncthreads();
    }
    if (t < nb) partials[t] = sh[t] - v;  // exclusive block offset
    if (t == 255) rs[n] = sh[t];          // grand total
}

// phase 3: add block offsets; cur = rs  (same SB blocking as phase 1)
__global__ __launch_bounds__(SB)
void k_scan3(int* __restrict__ rs, int* __restrict__ cur,
             const int* __restrict__ partials, int n) {
    int i = blockIdx.x * SB + threadIdx.x;
    if (i < n) {
        int v = rs[i] + partials[blockIdx.x];
        rs[i] = v;
        cur[i] = v;
    }
}

__global__ void k_scatter(const int* __restrict__ src, const int* __restrict__ dst,
                          int* __restrict__ cur, int* __restrict__ csr, int e) {
    int i = blockIdx.x * blockDim.x + threadIdx.x;
    if (i < e) {
        int d = dst[i];
        int pos = atomicAdd(&cur[d], 1);
        csr[pos] = src[i];
    }
}

// ---------------- gather-aggregate: agg[i] = x[i] + sum_{j in CSR[i]} x[j] ----------------
__global__ __launch_bounds__(256)
void k_gather(const float* __restrict__ x, const int* __restrict__ rs,
              const int* __restrict__ csr, float* __restrict__ agg, int n) {
    int wave = (blockIdx.x * blockDim.x + threadIdx.x) >> 6;
    int lane = threadIdx.x & 63;
    if (wave >= n) return;
    int beg = rs[wave], end = rs[wave + 1];
    const float2* xp = reinterpret_cast<const float2*>(x);
    float2 acc = xp[(size_t)wave * 64 + lane];
    int j = beg;
    for (; j + 4 <= end; j += 4) {
        int s0 = csr[j], s1 = csr[j + 1], s2 = csr[j + 2], s3 = csr[j + 3];
        float2 v0 = xp[(size_t)s0 * 64 + lane];
        float2 v1 = xp[(size_t)s1 * 64 + lane];
        float2 v2 = xp[(size_t)s2 * 64 + lane];
        float2 v3 = xp[(size_t)s3 * 64 + lane];
        acc.x += (v0.x + v1.x) + (v2.x + v3.x);
        acc.y += (v0.y + v1.y) + (v2.y + v3.y);
    }
    for (; j < end; ++j) {
        int s = csr[j];
        float2 v = xp[(size_t)s * 64 + lane];
        acc.x += v.x;
        acc.y += v.y;
    }
    reinterpret_cast<float2*>(agg)[(size_t)wave * 64 + lane] = acc;
}

// ---------------- row-streamed fp32 GEMM: out[r][c] = A[r][:] . W[:][c] + bias[c] ----------------
// One column per lane; W column held in 128 VGPRs per wave; A row is wave-uniform
// (readfirstlane -> s_load eligible). 4 accumulators break the FMA chain.
// 512 blocks * 4 waves = 2048 waves = exactly resident at 2 waves/SIMD.
template <bool BN_STATS, bool FUSE_OUT>
__global__ __launch_bounds__(256, 2)
void k_gemm(const float* __restrict__ A, const float* __restrict__ W,
            const float* __restrict__ bias, float* __restrict__ out,
            const float* __restrict__ xres, double* __restrict__ bn_sum,
            double* __restrict__ bn_sq, int nrows) {
    int wave = (blockIdx.x * blockDim.x + threadIdx.x) >> 6;
    int lane = threadIdx.x & 63;
    int half = wave & 1;
    int row0 = wave >> 1;
    int nstreams = (gridDim.x * blockDim.x) >> 7;
    int col = half * 64 + lane;

    float w[HID];
#pragma unroll
    for (int k = 0; k < HID; ++k) w[k] = W[k * HID + col];
    float b = bias[col];

    double s0 = 0.0, s1 = 0.0;

    for (int row = row0; row < nrows; row += nstreams) {
        int r = __builtin_amdgcn_readfirstlane(row);
        const float4* a4 = reinterpret_cast<const float4*>(A + (size_t)r * HID);
        float acc0 = 0.f, acc1 = 0.f, acc2 = 0.f, acc3 = 0.f;
#pragma unroll
        for (int kk = 0; kk < HID / 4; ++kk) {
            float4 av = a4[kk];
            acc0 = fmaf(av.x, w[4 * kk + 0], acc0);
            acc1 = fmaf(av.y, w[4 * kk + 1], acc1);
            acc2 = fmaf(av.z, w[4 * kk + 2], acc2);
            acc3 = fmaf(av.w, w[4 * kk + 3], acc3);
        }
        float v = ((acc0 + acc1) + (acc2 + acc3)) + b;
        if (FUSE_OUT) v = fmaxf(v, 0.f) + xres[(size_t)r * HID + col];
        out[(size_t)r * HID + col] = v;
        if (BN_STATS) {
            double vd = (double)v;
            s0 += vd;
            s1 = fma(vd, vd, s1);
        }
    }
    if (BN_STATS) {
        atomicAdd(&bn_sum[col], s0);
        atomicAdd(&bn_sq[col], s1);
    }
}

// ---------------- BN finalize: scale/shift per channel; self-zero stats for next layer ----
__global__ void k_bnfinal(double* __restrict__ sum, double* __restrict__ sq,
                          const float* __restrict__ gamma, const float* __restrict__ beta,
                          float* __restrict__ scale, float* __restrict__ shift, double inv_n) {
    int c = threadIdx.x;
    double m = sum[c] * inv_n;
    double var = sq[c] * inv_n - m * m;
    float sc = gamma[c] * rsqrtf((float)var + 1e-5f);
    scale[c] = sc;
    shift[c] = beta[c] - (float)m * sc;
    sum[c] = 0.0;
    sq[c] = 0.0;
}

// ---------------- BN apply + ReLU, in place ----------------
__global__ void k_bnapply(float* __restrict__ h, const float* __restrict__ scale,
                          const float* __restrict__ shift, int n4) {
    const float4* sc4 = reinterpret_cast<const float4*>(scale);
    const float4* sh4 = reinterpret_cast<const float4*>(shift);
    float4* h4 = reinterpret_cast<float4*>(h);
    int stride = gridDim.x * blockDim.x;
    for (int i = blockIdx.x * blockDim.x + threadIdx.x; i < n4; i += stride) {
        float4 v = h4[i];
        int c = i & 31;
        float4 a = sc4[c], bb = sh4[c];
        v.x = fmaxf(fmaf(v.x, a.x, bb.x), 0.f);
        v.y = fmaxf(fmaf(v.y, a.y, bb.y), 0.f);
        v.z = fmaxf(fmaf(v.z, a.z, bb.z), 0.f);
        v.w = fmaxf(fmaf(v.w, a.w, bb.w), 0.f);
        h4[i] = v;
    }
}

// ---------------- global_add_pool over sorted batch (int32) ----------------
__global__ void k_pool(const float* __restrict__ xf, const int* __restrict__ batch,
                       float* __restrict__ pooled, int n) {
    int g = blockIdx.x;
    int lo = 0, hi = n;
    while (lo < hi) { int mid = (lo + hi) >> 1; if (batch[mid] < g) lo = mid + 1; else hi = mid; }
    int beg = lo;
    lo = 0; hi = n;
    int g1 = g + 1;
    while (lo < hi) { int mid = (lo + hi) >> 1; if (batch[mid] < g1) lo = mid + 1; else hi = mid; }
    int end = lo;
    int t = threadIdx.x;
    float a0 = 0.f, a1 = 0.f, a2 = 0.f, a3 = 0.f;
    int r = beg;
    for (; r + 4 <= end; r += 4) {
        a0 += xf[(size_t)(r + 0) * HID + t];
        a1 += xf[(size_t)(r + 1) * HID + t];
        a2 += xf[(size_t)(r + 2) * HID + t];
        a3 += xf[(size_t)(r + 3) * HID + t];
    }
    for (; r < end; ++r) a0 += xf[(size_t)r * HID + t];
    pooled[(size_t)blockIdx.x * HID + t] = (a0 + a1) + (a2 + a3);
}

extern "C" void kernel_launch(void* const* d_in, const int* in_sizes, int n_in,
                              void* d_out, int out_size, void* d_ws, size_t ws_size,
                              hipStream_t stream) {
    const float* x      = (const float*)d_in[0];
    const int* ei       = (const int*)d_in[1];   // int32 per harness contract
    const int* batch    = (const int*)d_in[2];   // int32
    const float* W1     = (const float*)d_in[3];
    const float* b1     = (const float*)d_in[4];
    const float* gamma  = (const float*)d_in[5];
    const float* beta   = (const float*)d_in[6];
    const float* W2     = (const float*)d_in[7];
    const float* b2     = (const float*)d_in[8];

    const int N = in_sizes[0] / HID;
    const int E = in_sizes[1] / 2;
    const int L = in_sizes[3] / (HID * HID);
    const int G = (out_size - N * HID) / HID;

    const int* esrc = ei;
    const int* edst = ei + E;

    char* ws = (char*)d_ws;
    size_t off = 0;
    auto alloc = [&](size_t bytes) {
        void* p = ws + off;
        off += (bytes + 255) & ~(size_t)255;
        return p;
    };
    float* bufA = (float*)alloc((size_t)N * HID * 4);
    float* bufh = (float*)alloc((size_t)N * HID * 4);
    int* deg = (int*)alloc((size_t)N * 4);
    int* rs  = (int*)alloc(((size_t)N + 1) * 4);
    int* cur = (int*)alloc((size_t)N * 4);
    int* csr = (int*)alloc((size_t)E * 4);
    int* partials   = (int*)alloc(256 * 4);
    double* bn_sum  = (double*)alloc(HID * 8);
    double* bn_sq   = (double*)alloc(HID * 8);
    float* bn_scale = (float*)alloc(HID * 4);
    float* bn_shift = (float*)alloc(HID * 4);
    (void)ws_size;  // ~110MB

    float* xout   = (float*)d_out;
    float* pooled = (float*)d_out + (size_t)N * HID;
    float* bufB   = xout;  // d_out node region doubles as ping-pong scratch

    const int NB = (N + SB - 1) / SB;  // 98 <= 256

    // CSR by destination (rebuilt every call; identical work each call)
    hipMemsetAsync(deg, 0, (size_t)N * 4, stream);
    hipMemsetAsync(bn_sum, 0, HID * 8, stream);
    hipMemsetAsync(bn_sq, 0, HID * 8, stream);
    k_hist<<<(E + 255) / 256, 256, 0, stream>>>(edst, deg, E);
    k_scan1<<<NB, SB, 0, stream>>>(deg, rs, partials, N);
    k_scan2<<<1, 256, 0, stream>>>(partials, rs, NB, N);
    k_scan3<<<NB, SB, 0, stream>>>(rs, cur, partials, N);
    k_scatter<<<(E + 255) / 256, 256, 0, stream>>>(esrc, edst, cur, csr, E);

    // Buffer schedule (L=4): agg alternates A, B(=d_out), A, B; last layer's GEMM2
    // writes xout (same region as its agg — agg already consumed by GEMM1).
    const float* xl = x;
    for (int l = 0; l < L; ++l) {
        float* agg  = (l & 1) ? bufB : bufA;
        float* outb = (l == L - 1) ? xout : agg;

        k_gather<<<(N * 64 + 255) / 256, 256, 0, stream>>>(xl, rs, csr, agg, N);

        k_gemm<true, false><<<512, 256, 0, stream>>>(
            agg, W1 + (size_t)l * HID * HID, b1 + (size_t)l * HID, bufh,
            nullptr, bn_sum, bn_sq, N);
        k_bnfinal<<<1, HID, 0, stream>>>(bn_sum, bn_sq, gamma + (size_t)l * HID,
                                         beta + (size_t)l * HID, bn_scale, bn_shift,
                                         1.0 / (double)N);
        k_bnapply<<<2048, 256, 0, stream>>>(bufh, bn_scale, bn_shift, N * (HID / 4));
        k_gemm<false, true><<<512, 256, 0, stream>>>(
            bufh, W2 + (size_t)l * HID * HID, b2 + (size_t)l * HID, outb,
            xl, nullptr, nullptr, N);
        xl = outb;
    }

    k_pool<<<G, HID, 0, stream>>>(xout, batch, pooled, N);
}